// Round 1
// 268.904 us; speedup vs baseline: 1.0339x; 1.0339x over previous
//
#include <hip/hip_runtime.h>
#include <hip/hip_bf16.h>
#include <stdint.h>

#define NN 50000
#define NE 800000
#define NB 196            // dst buckets: dst>>8 (256 nodes each)
#define EPB 2048
#define NBLK ((NE + EPB - 1) / EPB)   // 391

typedef __attribute__((ext_vector_type(8))) __bf16 bf16x8;
typedef __attribute__((ext_vector_type(4))) float f32x4;
typedef __attribute__((ext_vector_type(4))) int i32x4;

__device__ __forceinline__ float bflo(uint32_t u) { return __uint_as_float(u << 16); }
__device__ __forceinline__ float bfhi(uint32_t u) { return __uint_as_float(u & 0xffff0000u); }
__device__ __forceinline__ uint16_t f2bf(float f) {
    uint32_t u = __float_as_uint(f);
    u += 0x7fffu + ((u >> 16) & 1u);   // RNE
    return (uint16_t)(u >> 16);
}
__device__ __forceinline__ float bf2f(uint16_t h) { return __uint_as_float(((uint32_t)h) << 16); }

// bijective XCD-chunked block swizzle (m204 variant): each XCD gets a
// contiguous chunk of tiles -> A-row panels stay in its private L2.
__device__ __forceinline__ int xcd_swz(int bid, int nwg) {
    int q = nwg >> 3, r = nwg & 7;
    int xcd = bid & 7, idx = bid >> 3;
    int base = (xcd < r) ? xcd * (q + 1) : r * (q + 1) + (xcd - r) * q;
    return base + idx;
}

// ---------------- dtype detection ----------------
__global__ __launch_bounds__(256) void detect(const uint32_t* __restrict__ xu,
                                              const int* __restrict__ ei,
                                              int* __restrict__ flags) {
    __shared__ int cnt_f, cnt_i;
    if (threadIdx.x == 0) { cnt_f = 0; cnt_i = 0; }
    __syncthreads();
    uint32_t u = xu[threadIdx.x];
    uint32_t lo = u & 0xffffu;
    uint32_t e = (lo >> 7) & 0xffu;
    int ok = (lo == 0u) || (e >= 96u && e <= 150u);
    atomicAdd(&cnt_f, ok);
    if (threadIdx.x < 64) {
        int w = ei[2 * threadIdx.x + 1];
        atomicAdd(&cnt_i, (w != 0) ? 1 : 0);
    }
    __syncthreads();
    if (threadIdx.x == 0) {
        flags[0] = (cnt_f < 192) ? 1 : 0;
        flags[1] = (cnt_i < 4) ? 1 : 0;
    }
}

// ---------------- pass 1: per-block bucket histograms (LDS atomics only) ----------------
__global__ __launch_bounds__(256) void hist_pass(const int* __restrict__ ei, const int* __restrict__ flags,
                                                 int* __restrict__ histM) {
    __shared__ int hist[NB];
    for (int i = threadIdx.x; i < NB; i += 256) hist[i] = 0;
    __syncthreads();
    int base = blockIdx.x * EPB;
    int fl = flags[1];
    for (int i = 0; i < EPB; i += 256) {
        int e = base + i + threadIdx.x;
        if (e < NE) {
            int d = fl ? ei[2 * NE + 2 * e] : ei[NE + e];
            atomicAdd(&hist[d >> 8], 1);
        }
    }
    __syncthreads();
    for (int i = threadIdx.x; i < NB; i += 256) histM[i * NBLK + blockIdx.x] = hist[i];
}

// ---------------- pass 2a: per-bucket scan over block counts ----------------
__global__ __launch_bounds__(512) void scan_rows(int* __restrict__ histM, int* __restrict__ bucket_tot) {
    __shared__ int sm[512];
    int b = blockIdx.x, t = threadIdx.x;
    int v = (t < NBLK) ? histM[b * NBLK + t] : 0;
    sm[t] = v;
    __syncthreads();
    for (int o = 1; o < 512; o <<= 1) {
        int x = (t >= o) ? sm[t - o] : 0;
        __syncthreads();
        sm[t] += x;
        __syncthreads();
    }
    if (t < NBLK) histM[b * NBLK + t] = sm[t] - v;   // exclusive prefix in-place
    if (t == 511) bucket_tot[b] = sm[511];
}

// ---------------- pass 2b: scan bucket totals -> bucket bases ----------------
__global__ __launch_bounds__(256) void scan_tot(const int* __restrict__ bucket_tot, int* __restrict__ bucket_base) {
    __shared__ int sm[256];
    int t = threadIdx.x;
    int v = (t < NB) ? bucket_tot[t] : 0;
    sm[t] = v;
    __syncthreads();
    for (int o = 1; o < 256; o <<= 1) {
        int x = (t >= o) ? sm[t - o] : 0;
        __syncthreads();
        sm[t] += x;
        __syncthreads();
    }
    if (t < NB) bucket_base[t] = sm[t] - v;
    if (t == 0) bucket_base[NB] = NE;
}

// ---------------- pass 3: scatter edges into reserved bucket runs (no global atomics) ----------------
// staging entry: (dst&0xff)<<16 | src   (NN < 2^16)
__global__ __launch_bounds__(256) void scatter_pass(const int* __restrict__ ei, const int* __restrict__ flags,
                                                    const int* __restrict__ histM, const int* __restrict__ bucket_base,
                                                    uint32_t* __restrict__ staging) {
    __shared__ int curs[NB];
    int blk = blockIdx.x, t = threadIdx.x;
    for (int i = t; i < NB; i += 256) curs[i] = bucket_base[i] + histM[i * NBLK + blk];
    __syncthreads();
    int base = blk * EPB;
    int fl = flags[1];
    for (int i = 0; i < EPB; i += 256) {
        int e = base + i + t;
        if (e < NE) {
            int s, d;
            if (fl) { s = ei[2 * e]; d = ei[2 * NE + 2 * e]; }
            else    { s = ei[e];     d = ei[NE + e]; }
            int p = atomicAdd(&curs[d >> 8], 1);
            staging[p] = ((uint32_t)(d & 0xff) << 16) | (uint32_t)s;
        }
    }
}

// ---------------- pass 4: per-bucket CSR build, all bookkeeping in LDS ----------------
__global__ __launch_bounds__(256) void build_csr(const uint32_t* __restrict__ staging,
                                                 const int* __restrict__ bucket_base,
                                                 int* __restrict__ row_start, int* __restrict__ deg,
                                                 float* __restrict__ inv_deg, int* __restrict__ csr) {
    __shared__ int degs[256];
    __shared__ int sm[256];
    __shared__ int curs[256];
    int b = blockIdx.x, t = threadIdx.x;
    int beg = bucket_base[b], cnt = bucket_base[b + 1] - beg;
    degs[t] = 0;
    __syncthreads();
    for (int i = t; i < cnt; i += 256) atomicAdd(&degs[(staging[beg + i] >> 16) & 0xff], 1);
    __syncthreads();
    int d = degs[t];
    sm[t] = d;
    __syncthreads();
    for (int o = 1; o < 256; o <<= 1) {
        int x = (t >= o) ? sm[t - o] : 0;
        __syncthreads();
        sm[t] += x;
        __syncthreads();
    }
    int excl = sm[t] - d;
    curs[t] = excl;
    int node = b * 256 + t;
    if (node < NN) {
        row_start[node] = beg + excl;
        deg[node] = d;
        inv_deg[node] = 1.0f / (float)(d > 0 ? d : 1);
    }
    __syncthreads();
    for (int i = t; i < cnt; i += 256) {
        uint32_t u = staging[beg + i];
        int dl = (u >> 16) & 0xff;
        int p = atomicAdd(&curs[dl], 1);
        csr[beg + p] = (int)(u & 0xffffu);
    }
}

__global__ __launch_bounds__(256) void norm_x(const void* __restrict__ x, const int* __restrict__ flags,
                                              uint32_t* __restrict__ out) {
    int i = blockIdx.x * 256 + threadIdx.x;  // < NN*64
    if (flags[0]) {
        float2 v = ((const float2*)x)[i];
        out[i] = (uint32_t)f2bf(v.x) | ((uint32_t)f2bf(v.y) << 16);
    } else {
        out[i] = ((const uint32_t*)x)[i];
    }
}

// ---------------- weights: normalize + swizzle into B-fragment layout ----------------
__global__ __launch_bounds__(256) void norm_weights_sw(const void* __restrict__ w1l, const void* __restrict__ b1,
                                                       const void* __restrict__ w1r, const void* __restrict__ w2l,
                                                       const void* __restrict__ b2, const void* __restrict__ w2r,
                                                       const int* __restrict__ flags,
                                                       uint16_t* __restrict__ w1l_sw, uint16_t* __restrict__ w1r_sw,
                                                       uint16_t* __restrict__ w2l_sw, uint16_t* __restrict__ w2r_sw,
                                                       uint16_t* __restrict__ bias_buf) {
    int tid = blockIdx.x * 256 + threadIdx.x;
    int fp32 = flags[0];
    if (tid < 16384) {
        int frag = tid >> 6, lane = tid & 63;
        const void* srcw; uint16_t* dst; int N; int fl;
        if (frag < 64)       { srcw = w1l; dst = w1l_sw; N = 256; fl = frag; }
        else if (frag < 128) { srcw = w1r; dst = w1r_sw; N = 256; fl = frag - 64; }
        else if (frag < 192) { srcw = w2l; dst = w2l_sw; N = 128; fl = frag - 128; }
        else                 { srcw = w2r; dst = w2r_sw; N = 128; fl = frag - 192; }
        int NTm = N >> 4;
        int kt = fl / NTm, nt = fl - kt * NTm;
        int k0 = kt * 32 + (lane >> 4) * 8, n = nt * 16 + (lane & 15);
        uint16_t* d = dst + (size_t)fl * 512 + lane * 8;
#pragma unroll
        for (int j = 0; j < 8; j++) {
            int si = (k0 + j) * N + n;
            d[j] = fp32 ? f2bf(((const float*)srcw)[si]) : ((const uint16_t*)srcw)[si];
        }
    } else if (tid < 16384 + 384) {
        int j = tid - 16384;
        const void* s = (j < 256) ? b1 : b2;
        int jj = (j < 256) ? j : j - 256;
        bias_buf[j] = fp32 ? f2bf(((const float*)s)[jj]) : ((const uint16_t*)s)[jj];
    }
}

// ---------------- mean aggregation (unroll 8) ----------------
__global__ __launch_bounds__(256) void agg_mean_128(const uint32_t* __restrict__ xu,
                                                    const int* __restrict__ row_start,
                                                    const int* __restrict__ deg,
                                                    const int* __restrict__ csr,
                                                    const float* __restrict__ inv_deg,
                                                    uint32_t* __restrict__ outu) {
    int node = blockIdx.x * 4 + (threadIdx.x >> 6);
    int lane = threadIdx.x & 63;
    int beg = row_start[node], end = beg + deg[node];
    float lo[8], hi[8];
#pragma unroll
    for (int k = 0; k < 8; k++) { lo[k] = 0.f; hi[k] = 0.f; }
    int j = beg;
    for (; j + 8 <= end; j += 8) {
        int idx[8];
#pragma unroll
        for (int k = 0; k < 8; k++) idx[k] = csr[j + k];
#pragma unroll
        for (int k = 0; k < 8; k++) {
            uint32_t u = xu[(size_t)idx[k] * 64 + lane];
            lo[k] += bflo(u); hi[k] += bfhi(u);
        }
    }
    for (; j < end; j++) {
        uint32_t u = xu[(size_t)csr[j] * 64 + lane];
        lo[0] += bflo(u); hi[0] += bfhi(u);
    }
    float sc = inv_deg[node];
    float r0 = (((lo[0] + lo[1]) + (lo[2] + lo[3])) + ((lo[4] + lo[5]) + (lo[6] + lo[7]))) * sc;
    float r1 = (((hi[0] + hi[1]) + (hi[2] + hi[3])) + ((hi[4] + hi[5]) + (hi[6] + hi[7]))) * sc;
    outu[(size_t)node * 64 + lane] = (uint32_t)f2bf(r0) | ((uint32_t)f2bf(r1) << 16);
}

// final: out = mean_gather(t) + u, fp32 out (unroll 8)
__global__ __launch_bounds__(256) void agg_final_128(const uint32_t* __restrict__ tu,
                                                     const int* __restrict__ row_start,
                                                     const int* __restrict__ deg,
                                                     const int* __restrict__ csr,
                                                     const float* __restrict__ inv_deg,
                                                     const float2* __restrict__ u,
                                                     float2* __restrict__ out) {
    int node = blockIdx.x * 4 + (threadIdx.x >> 6);
    int lane = threadIdx.x & 63;
    int beg = row_start[node], end = beg + deg[node];
    float lo[8], hi[8];
#pragma unroll
    for (int k = 0; k < 8; k++) { lo[k] = 0.f; hi[k] = 0.f; }
    int j = beg;
    for (; j + 8 <= end; j += 8) {
        int idx[8];
#pragma unroll
        for (int k = 0; k < 8; k++) idx[k] = csr[j + k];
#pragma unroll
        for (int k = 0; k < 8; k++) {
            uint32_t v = tu[(size_t)idx[k] * 64 + lane];
            lo[k] += bflo(v); hi[k] += bfhi(v);
        }
    }
    for (; j < end; j++) {
        uint32_t v = tu[(size_t)csr[j] * 64 + lane];
        lo[0] += bflo(v); hi[0] += bfhi(v);
    }
    float sc = inv_deg[node];
    float2 uv = u[(size_t)node * 64 + lane];
    float2 r;
    r.x = (((lo[0] + lo[1]) + (lo[2] + lo[3])) + ((lo[4] + lo[5]) + (lo[6] + lo[7]))) * sc + uv.x;
    r.y = (((hi[0] + hi[1]) + (hi[2] + hi[3])) + ((hi[4] + hi[5]) + (hi[6] + hi[7]))) * sc + uv.y;
    out[(size_t)node * 64 + lane] = r;
}

// ---------------- layer-1 GEMM v2: h = relu(A1@W1 + A2@W2 + bias) ----------------
// M=50000, K=128, N=256. Wave tile 32x32 (acc=16 VGPR), block 64x64, grid 782*4.
// Two sequential passes (one per weight matrix) with an asm fence so only one
// B-set (8 frags = 32 VGPR) is live at a time -> 4-5 waves/SIMD.
// Epilogue stages the 64x64 bf16 tile in LDS -> fully coalesced dwordx4 stores.
__global__ __launch_bounds__(256) void gemm1_v2(const uint16_t* __restrict__ A1,
                                                const uint16_t* __restrict__ A2,
                                                const uint16_t* __restrict__ W1sw,
                                                const uint16_t* __restrict__ W2sw,
                                                const uint16_t* __restrict__ bias,
                                                uint16_t* __restrict__ C) {
    __shared__ __align__(16) uint16_t cs[64][72];   // +8 pad, 144B row stride (16B aligned)
    int wg = xcd_swz(blockIdx.x, 3128);
    int rg = wg >> 2, cg = wg & 3;
    int wave = threadIdx.x >> 6, lane = threadIdx.x & 63;
    int wr = wave >> 1, wc = wave & 1;
    int m = lane & 15, q = lane >> 4;
    int rowbase = rg * 64 + wr * 32;
    int gnt0 = cg * 4 + wc * 2;      // global 16-col frag base, NTF=16

    int ar[2];
#pragma unroll
    for (int rf = 0; rf < 2; rf++) {
        int r = rowbase + rf * 16 + m;
        ar[rf] = (r < NN) ? r : (NN - 1);
    }

    f32x4 acc[2][2];
#pragma unroll
    for (int rf = 0; rf < 2; rf++)
#pragma unroll
        for (int nt = 0; nt < 2; nt++)
#pragma unroll
            for (int i = 0; i < 4; i++) acc[rf][nt][i] = 0.f;

    // ---- pass 1: A1 @ W1 ----
    {
        bf16x8 B[4][2];
#pragma unroll
        for (int kt = 0; kt < 4; kt++)
#pragma unroll
            for (int nt = 0; nt < 2; nt++)
                B[kt][nt] = *(const bf16x8*)(W1sw + ((size_t)(kt * 16 + gnt0 + nt)) * 512 + lane * 8);
#pragma unroll
        for (int kt = 0; kt < 4; kt++) {
            bf16x8 a0 = *(const bf16x8*)(A1 + (size_t)ar[0] * 128 + kt * 32 + q * 8);
            bf16x8 a1 = *(const bf16x8*)(A1 + (size_t)ar[1] * 128 + kt * 32 + q * 8);
#pragma unroll
            for (int nt = 0; nt < 2; nt++) {
                acc[0][nt] = __builtin_amdgcn_mfma_f32_16x16x32_bf16(a0, B[kt][nt], acc[0][nt], 0, 0, 0);
                acc[1][nt] = __builtin_amdgcn_mfma_f32_16x16x32_bf16(a1, B[kt][nt], acc[1][nt], 0, 0, 0);
            }
        }
    }
    asm volatile("" ::: "memory");   // fence: keep pass-2 B loads out of pass 1 (caps live VGPRs)
    // ---- pass 2: A2 @ W2 ----
    {
        bf16x8 B[4][2];
#pragma unroll
        for (int kt = 0; kt < 4; kt++)
#pragma unroll
            for (int nt = 0; nt < 2; nt++)
                B[kt][nt] = *(const bf16x8*)(W2sw + ((size_t)(kt * 16 + gnt0 + nt)) * 512 + lane * 8);
#pragma unroll
        for (int kt = 0; kt < 4; kt++) {
            bf16x8 a0 = *(const bf16x8*)(A2 + (size_t)ar[0] * 128 + kt * 32 + q * 8);
            bf16x8 a1 = *(const bf16x8*)(A2 + (size_t)ar[1] * 128 + kt * 32 + q * 8);
#pragma unroll
            for (int nt = 0; nt < 2; nt++) {
                acc[0][nt] = __builtin_amdgcn_mfma_f32_16x16x32_bf16(a0, B[kt][nt], acc[0][nt], 0, 0, 0);
                acc[1][nt] = __builtin_amdgcn_mfma_f32_16x16x32_bf16(a1, B[kt][nt], acc[1][nt], 0, 0, 0);
            }
        }
    }

    // ---- epilogue: bias + relu -> LDS -> coalesced store ----
#pragma unroll
    for (int rf = 0; rf < 2; rf++)
#pragma unroll
        for (int nt = 0; nt < 2; nt++) {
            int coll = wc * 32 + nt * 16 + m;
            float bv = bf2f(bias[cg * 64 + coll]);
#pragma unroll
            for (int i = 0; i < 4; i++) {
                float v = fmaxf(acc[rf][nt][i] + bv, 0.f);
                cs[wr * 32 + rf * 16 + q * 4 + i][coll] = f2bf(v);
            }
        }
    __syncthreads();
    int tt = threadIdx.x;
#pragma unroll
    for (int rr = 0; rr < 2; rr++) {
        int row = rr * 32 + (tt >> 3);
        int grow = rg * 64 + row;
        if (grow < NN)
            *(i32x4*)(C + (size_t)grow * 256 + cg * 64 + (tt & 7) * 8) =
                *(const i32x4*)&cs[row][(tt & 7) * 8];
    }
}

// ---------------- layer-2 GEMM v2: t = A@W1 (bf16), u = A@W2 + bias (fp32) ----------------
// M=50000, K=256, N=128. Wave tile 32x32, block 64x64, grid 782*2.
// Sequential B-matrix passes (B live-set 16 frags = 64 VGPR), A re-read from L2.
__global__ __launch_bounds__(256) void gemm2_v2(const uint16_t* __restrict__ A,
                                                const uint16_t* __restrict__ W1sw,
                                                const uint16_t* __restrict__ W2sw,
                                                const uint16_t* __restrict__ bias,
                                                uint16_t* __restrict__ T,
                                                float* __restrict__ U) {
    __shared__ __align__(16) uint16_t ts[64][72];   // 9216 B
    __shared__ __align__(16) float us[64][68];      // 17408 B
    int wg = xcd_swz(blockIdx.x, 1564);
    int rg = wg >> 1, cg = wg & 1;
    int wave = threadIdx.x >> 6, lane = threadIdx.x & 63;
    int wr = wave >> 1, wc = wave & 1;
    int m = lane & 15, q = lane >> 4;
    int rowbase = rg * 64 + wr * 32;
    int gnt0 = cg * 4 + wc * 2;      // global 16-col frag base, NTF=8

    int ar[2];
#pragma unroll
    for (int rf = 0; rf < 2; rf++) {
        int r = rowbase + rf * 16 + m;
        ar[rf] = (r < NN) ? r : (NN - 1);
    }

    f32x4 acc1[2][2], acc2[2][2];
#pragma unroll
    for (int rf = 0; rf < 2; rf++)
#pragma unroll
        for (int nt = 0; nt < 2; nt++)
#pragma unroll
            for (int i = 0; i < 4; i++) { acc1[rf][nt][i] = 0.f; acc2[rf][nt][i] = 0.f; }

    // ---- pass 1: A @ W1 -> acc1 ----
    {
        bf16x8 B[8][2];
#pragma unroll
        for (int kt = 0; kt < 8; kt++)
#pragma unroll
            for (int nt = 0; nt < 2; nt++)
                B[kt][nt] = *(const bf16x8*)(W1sw + ((size_t)(kt * 8 + gnt0 + nt)) * 512 + lane * 8);
#pragma unroll
        for (int kt = 0; kt < 8; kt++) {
            bf16x8 a0 = *(const bf16x8*)(A + (size_t)ar[0] * 256 + kt * 32 + q * 8);
            bf16x8 a1 = *(const bf16x8*)(A + (size_t)ar[1] * 256 + kt * 32 + q * 8);
#pragma unroll
            for (int nt = 0; nt < 2; nt++) {
                acc1[0][nt] = __builtin_amdgcn_mfma_f32_16x16x32_bf16(a0, B[kt][nt], acc1[0][nt], 0, 0, 0);
                acc1[1][nt] = __builtin_amdgcn_mfma_f32_16x16x32_bf16(a1, B[kt][nt], acc1[1][nt], 0, 0, 0);
            }
        }
    }
    asm volatile("" ::: "memory");   // fence: cap live B regs at one pass's worth
    // ---- pass 2: A @ W2 -> acc2 ----
    {
        bf16x8 B[8][2];
#pragma unroll
        for (int kt = 0; kt < 8; kt++)
#pragma unroll
            for (int nt = 0; nt < 2; nt++)
                B[kt][nt] = *(const bf16x8*)(W2sw + ((size_t)(kt * 8 + gnt0 + nt)) * 512 + lane * 8);
#pragma unroll
        for (int kt = 0; kt < 8; kt++) {
            bf16x8 a0 = *(const bf16x8*)(A + (size_t)ar[0] * 256 + kt * 32 + q * 8);
            bf16x8 a1 = *(const bf16x8*)(A + (size_t)ar[1] * 256 + kt * 32 + q * 8);
#pragma unroll
            for (int nt = 0; nt < 2; nt++) {
                acc2[0][nt] = __builtin_amdgcn_mfma_f32_16x16x32_bf16(a0, B[kt][nt], acc2[0][nt], 0, 0, 0);
                acc2[1][nt] = __builtin_amdgcn_mfma_f32_16x16x32_bf16(a1, B[kt][nt], acc2[1][nt], 0, 0, 0);
            }
        }
    }

    // ---- epilogue: t (raw bf16) and u (bias-added fp32) via LDS, coalesced ----
#pragma unroll
    for (int rf = 0; rf < 2; rf++)
#pragma unroll
        for (int nt = 0; nt < 2; nt++) {
            int coll = wc * 32 + nt * 16 + m;
            float bv = bf2f(bias[cg * 64 + coll]);
#pragma unroll
            for (int i = 0; i < 4; i++) {
                int rl = wr * 32 + rf * 16 + q * 4 + i;
                ts[rl][coll] = f2bf(acc1[rf][nt][i]);
                us[rl][coll] = acc2[rf][nt][i] + bv;
            }
        }
    __syncthreads();
    int tt = threadIdx.x;
#pragma unroll
    for (int rr = 0; rr < 2; rr++) {
        int row = rr * 32 + (tt >> 3);
        int grow = rg * 64 + row;
        if (grow < NN)
            *(i32x4*)(T + (size_t)grow * 128 + cg * 64 + (tt & 7) * 8) =
                *(const i32x4*)&ts[row][(tt & 7) * 8];
    }
#pragma unroll
    for (int rr = 0; rr < 4; rr++) {
        int row = rr * 16 + (tt >> 4);
        int grow = rg * 64 + row;
        if (grow < NN)
            *(f32x4*)(U + (size_t)grow * 128 + cg * 64 + (tt & 15) * 4) =
                *(const f32x4*)&us[row][(tt & 15) * 4];
    }
}

extern "C" void kernel_launch(void* const* d_in, const int* in_sizes, int n_in,
                              void* d_out, int out_size, void* d_ws, size_t ws_size,
                              hipStream_t stream) {
    const void* x_raw  = d_in[0];
    const int*  ei     = (const int*)d_in[1];
    const void* W1l    = d_in[2];
    const void* b1     = d_in[3];
    const void* W1r    = d_in[4];
    const void* W2l    = d_in[5];
    const void* b2     = d_in[6];
    const void* W2r    = d_in[7];

    uint8_t* ws = (uint8_t*)d_ws;
    size_t off = 0;
    auto alloc = [&](size_t b) -> void* {
        void* p = ws + off;
        off += (b + 255) & ~(size_t)255;
        return p;
    };
    int*      flags       = (int*)alloc(256);
    int*      histM       = (int*)alloc((size_t)NB * NBLK * 4);
    int*      bucket_tot  = (int*)alloc((NB + 4) * 4);
    int*      bucket_base = (int*)alloc((NB + 4) * 4);
    int*      deg         = (int*)alloc((size_t)NN * 4);
    float*    inv_deg     = (float*)alloc((size_t)NN * 4);
    int*      row_start   = (int*)alloc((size_t)NN * 4);
    int*      csr         = (int*)alloc((size_t)NE * 4);
    uint32_t* xb          = (uint32_t*)alloc((size_t)NN * 64 * 4);
    uint16_t* bias_buf    = (uint16_t*)alloc(384 * 2);
    uint16_t* agg         = (uint16_t*)alloc((size_t)NN * 128 * 2);
    uint16_t* h           = (uint16_t*)alloc((size_t)NN * 256 * 2);
    uint16_t* t           = (uint16_t*)alloc((size_t)NN * 128 * 2);
    float*    u           = (float*)alloc((size_t)NN * 128 * 4);
    uint16_t* w1l_sw      = (uint16_t*)alloc(128 * 256 * 2);
    uint16_t* w1r_sw      = (uint16_t*)alloc(128 * 256 * 2);
    uint16_t* w2l_sw      = (uint16_t*)alloc(256 * 128 * 2);
    uint16_t* w2r_sw      = (uint16_t*)alloc(256 * 128 * 2);

    // staging aliases h (3.2 MB <= 25.6 MB; fully consumed by build_csr before h is written)
    uint32_t* staging = (uint32_t*)h;

    detect<<<1, 256, 0, stream>>>((const uint32_t*)x_raw, ei, flags);

    hist_pass<<<NBLK, 256, 0, stream>>>(ei, flags, histM);
    scan_rows<<<NB, 512, 0, stream>>>(histM, bucket_tot);
    scan_tot<<<1, 256, 0, stream>>>(bucket_tot, bucket_base);
    scatter_pass<<<NBLK, 256, 0, stream>>>(ei, flags, histM, bucket_base, staging);
    build_csr<<<NB, 256, 0, stream>>>(staging, bucket_base, row_start, deg, inv_deg, csr);

    norm_x<<<(NN * 64 + 255) / 256, 256, 0, stream>>>(x_raw, flags, xb);
    norm_weights_sw<<<66, 256, 0, stream>>>(W1l, b1, W1r, W2l, b2, W2r, flags,
                                            w1l_sw, w1r_sw, w2l_sw, w2r_sw, bias_buf);

    // layer 1: agg = A·x ; h = relu(agg@W1l + x@W1r + b1)
    agg_mean_128<<<NN / 4, 256, 0, stream>>>(xb, row_start, deg, csr, inv_deg, (uint32_t*)agg);
    gemm1_v2<<<3128, 256, 0, stream>>>(agg, (const uint16_t*)xb, w1l_sw, w1r_sw, bias_buf, h);
    // layer 2: t = h@W2l, u = h@W2r + b2 ; out = A·t + u
    gemm2_v2<<<1564, 256, 0, stream>>>(h, w2l_sw, w2r_sw, bias_buf + 256, t, u);
    agg_final_128<<<NN / 4, 256, 0, stream>>>((const uint32_t*)t, row_start, deg, csr, inv_deg,
                                              (const float2*)u, (float2*)d_out);
}

// Round 2
// 267.383 us; speedup vs baseline: 1.0398x; 1.0057x over previous
//
#include <hip/hip_runtime.h>
#include <hip/hip_bf16.h>
#include <stdint.h>

#define NN 50000
#define NE 800000
#define NB 196            // dst buckets: dst>>8 (256 nodes each)
#define EPB 2048
#define NBLK ((NE + EPB - 1) / EPB)   // 391

typedef __attribute__((ext_vector_type(8))) __bf16 bf16x8;
typedef __attribute__((ext_vector_type(4))) float f32x4;
typedef __attribute__((ext_vector_type(4))) int i32x4;

__device__ __forceinline__ float bflo(uint32_t u) { return __uint_as_float(u << 16); }
__device__ __forceinline__ float bfhi(uint32_t u) { return __uint_as_float(u & 0xffff0000u); }
__device__ __forceinline__ uint16_t f2bf(float f) {
    uint32_t u = __float_as_uint(f);
    u += 0x7fffu + ((u >> 16) & 1u);   // RNE
    return (uint16_t)(u >> 16);
}
__device__ __forceinline__ float bf2f(uint16_t h) { return __uint_as_float(((uint32_t)h) << 16); }

// bijective XCD-chunked block swizzle (m204 variant)
__device__ __forceinline__ int xcd_swz(int bid, int nwg) {
    int q = nwg >> 3, r = nwg & 7;
    int xcd = bid & 7, idx = bid >> 3;
    int base = (xcd < r) ? xcd * (q + 1) : r * (q + 1) + (xcd - r) * q;
    return base + idx;
}

// ---------------- dtype detection ----------------
__global__ __launch_bounds__(256) void detect(const uint32_t* __restrict__ xu,
                                              const int* __restrict__ ei,
                                              int* __restrict__ flags) {
    __shared__ int cnt_f, cnt_i;
    if (threadIdx.x == 0) { cnt_f = 0; cnt_i = 0; }
    __syncthreads();
    uint32_t u = xu[threadIdx.x];
    uint32_t lo = u & 0xffffu;
    uint32_t e = (lo >> 7) & 0xffu;
    int ok = (lo == 0u) || (e >= 96u && e <= 150u);
    atomicAdd(&cnt_f, ok);
    if (threadIdx.x < 64) {
        int w = ei[2 * threadIdx.x + 1];
        atomicAdd(&cnt_i, (w != 0) ? 1 : 0);
    }
    __syncthreads();
    if (threadIdx.x == 0) {
        flags[0] = (cnt_f < 192) ? 1 : 0;
        flags[1] = (cnt_i < 4) ? 1 : 0;
    }
}

// ---------------- pass 1: per-block bucket histograms (LDS atomics only) ----------------
__global__ __launch_bounds__(256) void hist_pass(const int* __restrict__ ei, const int* __restrict__ flags,
                                                 int* __restrict__ histM) {
    __shared__ int hist[NB];
    for (int i = threadIdx.x; i < NB; i += 256) hist[i] = 0;
    __syncthreads();
    int base = blockIdx.x * EPB;
    int fl = flags[1];
    for (int i = 0; i < EPB; i += 256) {
        int e = base + i + threadIdx.x;
        if (e < NE) {
            int d = fl ? ei[2 * NE + 2 * e] : ei[NE + e];
            atomicAdd(&hist[d >> 8], 1);
        }
    }
    __syncthreads();
    for (int i = threadIdx.x; i < NB; i += 256) histM[i * NBLK + blockIdx.x] = hist[i];
}

// ---------------- pass 2a: per-bucket scan over block counts ----------------
__global__ __launch_bounds__(512) void scan_rows(int* __restrict__ histM, int* __restrict__ bucket_tot) {
    __shared__ int sm[512];
    int b = blockIdx.x, t = threadIdx.x;
    int v = (t < NBLK) ? histM[b * NBLK + t] : 0;
    sm[t] = v;
    __syncthreads();
    for (int o = 1; o < 512; o <<= 1) {
        int x = (t >= o) ? sm[t - o] : 0;
        __syncthreads();
        sm[t] += x;
        __syncthreads();
    }
    if (t < NBLK) histM[b * NBLK + t] = sm[t] - v;   // exclusive prefix in-place
    if (t == 511) bucket_tot[b] = sm[511];
}

// ---------------- pass 2b: scan bucket totals -> bucket bases ----------------
__global__ __launch_bounds__(256) void scan_tot(const int* __restrict__ bucket_tot, int* __restrict__ bucket_base) {
    __shared__ int sm[256];
    int t = threadIdx.x;
    int v = (t < NB) ? bucket_tot[t] : 0;
    sm[t] = v;
    __syncthreads();
    for (int o = 1; o < 256; o <<= 1) {
        int x = (t >= o) ? sm[t - o] : 0;
        __syncthreads();
        sm[t] += x;
        __syncthreads();
    }
    if (t < NB) bucket_base[t] = sm[t] - v;
    if (t == 0) bucket_base[NB] = NE;
}

// ---------------- pass 3: scatter edges into reserved bucket runs ----------------
__global__ __launch_bounds__(256) void scatter_pass(const int* __restrict__ ei, const int* __restrict__ flags,
                                                    const int* __restrict__ histM, const int* __restrict__ bucket_base,
                                                    uint32_t* __restrict__ staging) {
    __shared__ int curs[NB];
    int blk = blockIdx.x, t = threadIdx.x;
    for (int i = t; i < NB; i += 256) curs[i] = bucket_base[i] + histM[i * NBLK + blk];
    __syncthreads();
    int base = blk * EPB;
    int fl = flags[1];
    for (int i = 0; i < EPB; i += 256) {
        int e = base + i + t;
        if (e < NE) {
            int s, d;
            if (fl) { s = ei[2 * e]; d = ei[2 * NE + 2 * e]; }
            else    { s = ei[e];     d = ei[NE + e]; }
            int p = atomicAdd(&curs[d >> 8], 1);
            staging[p] = ((uint32_t)(d & 0xff) << 16) | (uint32_t)s;
        }
    }
}

// ---------------- pass 4: per-bucket CSR build ----------------
__global__ __launch_bounds__(256) void build_csr(const uint32_t* __restrict__ staging,
                                                 const int* __restrict__ bucket_base,
                                                 int* __restrict__ row_start, int* __restrict__ deg,
                                                 float* __restrict__ inv_deg, int* __restrict__ csr) {
    __shared__ int degs[256];
    __shared__ int sm[256];
    __shared__ int curs[256];
    int b = blockIdx.x, t = threadIdx.x;
    int beg = bucket_base[b], cnt = bucket_base[b + 1] - beg;
    degs[t] = 0;
    __syncthreads();
    for (int i = t; i < cnt; i += 256) atomicAdd(&degs[(staging[beg + i] >> 16) & 0xff], 1);
    __syncthreads();
    int d = degs[t];
    sm[t] = d;
    __syncthreads();
    for (int o = 1; o < 256; o <<= 1) {
        int x = (t >= o) ? sm[t - o] : 0;
        __syncthreads();
        sm[t] += x;
        __syncthreads();
    }
    int excl = sm[t] - d;
    curs[t] = excl;
    int node = b * 256 + t;
    if (node < NN) {
        row_start[node] = beg + excl;
        deg[node] = d;
        inv_deg[node] = 1.0f / (float)(d > 0 ? d : 1);
    }
    __syncthreads();
    for (int i = t; i < cnt; i += 256) {
        uint32_t u = staging[beg + i];
        int dl = (u >> 16) & 0xff;
        int p = atomicAdd(&curs[dl], 1);
        csr[beg + p] = (int)(u & 0xffffu);
    }
}

// norm_x v2: 2 packed uint32 outputs per thread (float4 in / uint2 out)
__global__ __launch_bounds__(256) void norm_x(const void* __restrict__ x, const int* __restrict__ flags,
                                              uint32_t* __restrict__ out) {
    int i = blockIdx.x * 256 + threadIdx.x;  // < NN*32
    if (flags[0]) {
        f32x4 v = ((const f32x4*)x)[i];
        uint2 o;
        o.x = (uint32_t)f2bf(v[0]) | ((uint32_t)f2bf(v[1]) << 16);
        o.y = (uint32_t)f2bf(v[2]) | ((uint32_t)f2bf(v[3]) << 16);
        ((uint2*)out)[i] = o;
    } else {
        ((uint2*)out)[i] = ((const uint2*)x)[i];
    }
}

// ---------------- weights: normalize + swizzle into B-fragment layout ----------------
__global__ __launch_bounds__(256) void norm_weights_sw(const void* __restrict__ w1l, const void* __restrict__ b1,
                                                       const void* __restrict__ w1r, const void* __restrict__ w2l,
                                                       const void* __restrict__ b2, const void* __restrict__ w2r,
                                                       const int* __restrict__ flags,
                                                       uint16_t* __restrict__ w1l_sw, uint16_t* __restrict__ w1r_sw,
                                                       uint16_t* __restrict__ w2l_sw, uint16_t* __restrict__ w2r_sw,
                                                       uint16_t* __restrict__ bias_buf) {
    int tid = blockIdx.x * 256 + threadIdx.x;
    int fp32 = flags[0];
    if (tid < 16384) {
        int frag = tid >> 6, lane = tid & 63;
        const void* srcw; uint16_t* dst; int N; int fl;
        if (frag < 64)       { srcw = w1l; dst = w1l_sw; N = 256; fl = frag; }
        else if (frag < 128) { srcw = w1r; dst = w1r_sw; N = 256; fl = frag - 64; }
        else if (frag < 192) { srcw = w2l; dst = w2l_sw; N = 128; fl = frag - 128; }
        else                 { srcw = w2r; dst = w2r_sw; N = 128; fl = frag - 192; }
        int NTm = N >> 4;
        int kt = fl / NTm, nt = fl - kt * NTm;
        int k0 = kt * 32 + (lane >> 4) * 8, n = nt * 16 + (lane & 15);
        uint16_t* d = dst + (size_t)fl * 512 + lane * 8;
#pragma unroll
        for (int j = 0; j < 8; j++) {
            int si = (k0 + j) * N + n;
            d[j] = fp32 ? f2bf(((const float*)srcw)[si]) : ((const uint16_t*)srcw)[si];
        }
    } else if (tid < 16384 + 384) {
        int j = tid - 16384;
        const void* s = (j < 256) ? b1 : b2;
        int jj = (j < 256) ? j : j - 256;
        bias_buf[j] = fp32 ? f2bf(((const float*)s)[jj]) : ((const uint16_t*)s)[jj];
    }
}

// ---------------- mean aggregation v2: 2 nodes/wave, dwordx2 gathers ----------------
// Each 32-lane half-wave owns one node; lane l loads 8 B (4 bf16 dims) per edge.
// 512 B / gather instruction, 2x rows in flight vs v1.
__global__ __launch_bounds__(256) void agg_mean_v2(const uint32_t* __restrict__ xu,
                                                   const int* __restrict__ row_start,
                                                   const int* __restrict__ deg,
                                                   const int* __restrict__ csr,
                                                   const float* __restrict__ inv_deg,
                                                   uint32_t* __restrict__ outu) {
    int wave = threadIdx.x >> 6, lane = threadIdx.x & 63;
    int half = lane >> 5, l = lane & 31;
    int node = blockIdx.x * 8 + wave * 2 + half;
    int beg = row_start[node], end = beg + deg[node];
    float lx[8], hx[8], ly[8], hy[8];
#pragma unroll
    for (int k = 0; k < 8; k++) { lx[k] = 0.f; hx[k] = 0.f; ly[k] = 0.f; hy[k] = 0.f; }
    int j = beg;
    for (; j + 8 <= end; j += 8) {
        int idx[8];
#pragma unroll
        for (int k = 0; k < 8; k++) idx[k] = csr[j + k];
#pragma unroll
        for (int k = 0; k < 8; k++) {
            uint2 v = *(const uint2*)(xu + (size_t)idx[k] * 64 + l * 2);
            lx[k] += bflo(v.x); hx[k] += bfhi(v.x);
            ly[k] += bflo(v.y); hy[k] += bfhi(v.y);
        }
    }
    for (; j < end; j++) {
        uint2 v = *(const uint2*)(xu + (size_t)csr[j] * 64 + l * 2);
        lx[0] += bflo(v.x); hx[0] += bfhi(v.x);
        ly[0] += bflo(v.y); hy[0] += bfhi(v.y);
    }
    float sc = inv_deg[node];
    float r0 = (((lx[0] + lx[1]) + (lx[2] + lx[3])) + ((lx[4] + lx[5]) + (lx[6] + lx[7]))) * sc;
    float r1 = (((hx[0] + hx[1]) + (hx[2] + hx[3])) + ((hx[4] + hx[5]) + (hx[6] + hx[7]))) * sc;
    float r2 = (((ly[0] + ly[1]) + (ly[2] + ly[3])) + ((ly[4] + ly[5]) + (ly[6] + ly[7]))) * sc;
    float r3 = (((hy[0] + hy[1]) + (hy[2] + hy[3])) + ((hy[4] + hy[5]) + (hy[6] + hy[7]))) * sc;
    uint2 o;
    o.x = (uint32_t)f2bf(r0) | ((uint32_t)f2bf(r1) << 16);
    o.y = (uint32_t)f2bf(r2) | ((uint32_t)f2bf(r3) << 16);
    *(uint2*)(outu + (size_t)node * 64 + l * 2) = o;
}

// final v2: out = mean_gather(t) + u, fp32 out; 2 nodes/wave, dwordx2 gathers, float4 stores
__global__ __launch_bounds__(256) void agg_final_v2(const uint32_t* __restrict__ tu,
                                                    const int* __restrict__ row_start,
                                                    const int* __restrict__ deg,
                                                    const int* __restrict__ csr,
                                                    const float* __restrict__ inv_deg,
                                                    const f32x4* __restrict__ u,
                                                    f32x4* __restrict__ out) {
    int wave = threadIdx.x >> 6, lane = threadIdx.x & 63;
    int half = lane >> 5, l = lane & 31;
    int node = blockIdx.x * 8 + wave * 2 + half;
    int beg = row_start[node], end = beg + deg[node];
    float lx[8], hx[8], ly[8], hy[8];
#pragma unroll
    for (int k = 0; k < 8; k++) { lx[k] = 0.f; hx[k] = 0.f; ly[k] = 0.f; hy[k] = 0.f; }
    int j = beg;
    for (; j + 8 <= end; j += 8) {
        int idx[8];
#pragma unroll
        for (int k = 0; k < 8; k++) idx[k] = csr[j + k];
#pragma unroll
        for (int k = 0; k < 8; k++) {
            uint2 v = *(const uint2*)(tu + (size_t)idx[k] * 64 + l * 2);
            lx[k] += bflo(v.x); hx[k] += bfhi(v.x);
            ly[k] += bflo(v.y); hy[k] += bfhi(v.y);
        }
    }
    for (; j < end; j++) {
        uint2 v = *(const uint2*)(tu + (size_t)csr[j] * 64 + l * 2);
        lx[0] += bflo(v.x); hx[0] += bfhi(v.x);
        ly[0] += bflo(v.y); hy[0] += bfhi(v.y);
    }
    float sc = inv_deg[node];
    f32x4 uv = u[(size_t)node * 32 + l];
    f32x4 r;
    r[0] = (((lx[0] + lx[1]) + (lx[2] + lx[3])) + ((lx[4] + lx[5]) + (lx[6] + lx[7]))) * sc + uv[0];
    r[1] = (((hx[0] + hx[1]) + (hx[2] + hx[3])) + ((hx[4] + hx[5]) + (hx[6] + hx[7]))) * sc + uv[1];
    r[2] = (((ly[0] + ly[1]) + (ly[2] + ly[3])) + ((ly[4] + ly[5]) + (ly[6] + ly[7]))) * sc + uv[2];
    r[3] = (((hy[0] + hy[1]) + (hy[2] + hy[3])) + ((hy[4] + hy[5]) + (hy[6] + hy[7]))) * sc + uv[3];
    out[(size_t)node * 32 + l] = r;
}

// ---------------- layer-1 GEMM v2: h = relu(A1@W1 + A2@W2 + bias) ----------------
__global__ __launch_bounds__(256) void gemm1_v2(const uint16_t* __restrict__ A1,
                                                const uint16_t* __restrict__ A2,
                                                const uint16_t* __restrict__ W1sw,
                                                const uint16_t* __restrict__ W2sw,
                                                const uint16_t* __restrict__ bias,
                                                uint16_t* __restrict__ C) {
    __shared__ __align__(16) uint16_t cs[64][72];   // +8 pad, 144B row stride (16B aligned)
    int wg = xcd_swz(blockIdx.x, 3128);
    int rg = wg >> 2, cg = wg & 3;
    int wave = threadIdx.x >> 6, lane = threadIdx.x & 63;
    int wr = wave >> 1, wc = wave & 1;
    int m = lane & 15, q = lane >> 4;
    int rowbase = rg * 64 + wr * 32;
    int gnt0 = cg * 4 + wc * 2;      // global 16-col frag base, NTF=16

    int ar[2];
#pragma unroll
    for (int rf = 0; rf < 2; rf++) {
        int r = rowbase + rf * 16 + m;
        ar[rf] = (r < NN) ? r : (NN - 1);
    }

    f32x4 acc[2][2];
#pragma unroll
    for (int rf = 0; rf < 2; rf++)
#pragma unroll
        for (int nt = 0; nt < 2; nt++)
#pragma unroll
            for (int i = 0; i < 4; i++) acc[rf][nt][i] = 0.f;

    // ---- pass 1: A1 @ W1 ----
    {
        bf16x8 B[4][2];
#pragma unroll
        for (int kt = 0; kt < 4; kt++)
#pragma unroll
            for (int nt = 0; nt < 2; nt++)
                B[kt][nt] = *(const bf16x8*)(W1sw + ((size_t)(kt * 16 + gnt0 + nt)) * 512 + lane * 8);
#pragma unroll
        for (int kt = 0; kt < 4; kt++) {
            bf16x8 a0 = *(const bf16x8*)(A1 + (size_t)ar[0] * 128 + kt * 32 + q * 8);
            bf16x8 a1 = *(const bf16x8*)(A1 + (size_t)ar[1] * 128 + kt * 32 + q * 8);
#pragma unroll
            for (int nt = 0; nt < 2; nt++) {
                acc[0][nt] = __builtin_amdgcn_mfma_f32_16x16x32_bf16(a0, B[kt][nt], acc[0][nt], 0, 0, 0);
                acc[1][nt] = __builtin_amdgcn_mfma_f32_16x16x32_bf16(a1, B[kt][nt], acc[1][nt], 0, 0, 0);
            }
        }
    }
    asm volatile("" ::: "memory");   // fence: keep pass-2 B loads out of pass 1 (caps live VGPRs)
    // ---- pass 2: A2 @ W2 ----
    {
        bf16x8 B[4][2];
#pragma unroll
        for (int kt = 0; kt < 4; kt++)
#pragma unroll
            for (int nt = 0; nt < 2; nt++)
                B[kt][nt] = *(const bf16x8*)(W2sw + ((size_t)(kt * 16 + gnt0 + nt)) * 512 + lane * 8);
#pragma unroll
        for (int kt = 0; kt < 4; kt++) {
            bf16x8 a0 = *(const bf16x8*)(A2 + (size_t)ar[0] * 128 + kt * 32 + q * 8);
            bf16x8 a1 = *(const bf16x8*)(A2 + (size_t)ar[1] * 128 + kt * 32 + q * 8);
#pragma unroll
            for (int nt = 0; nt < 2; nt++) {
                acc[0][nt] = __builtin_amdgcn_mfma_f32_16x16x32_bf16(a0, B[kt][nt], acc[0][nt], 0, 0, 0);
                acc[1][nt] = __builtin_amdgcn_mfma_f32_16x16x32_bf16(a1, B[kt][nt], acc[1][nt], 0, 0, 0);
            }
        }
    }

    // ---- epilogue: bias + relu -> LDS -> coalesced store ----
#pragma unroll
    for (int rf = 0; rf < 2; rf++)
#pragma unroll
        for (int nt = 0; nt < 2; nt++) {
            int coll = wc * 32 + nt * 16 + m;
            float bv = bf2f(bias[cg * 64 + coll]);
#pragma unroll
            for (int i = 0; i < 4; i++) {
                float v = fmaxf(acc[rf][nt][i] + bv, 0.f);
                cs[wr * 32 + rf * 16 + q * 4 + i][coll] = f2bf(v);
            }
        }
    __syncthreads();
    int tt = threadIdx.x;
#pragma unroll
    for (int rr = 0; rr < 2; rr++) {
        int row = rr * 32 + (tt >> 3);
        int grow = rg * 64 + row;
        if (grow < NN)
            *(i32x4*)(C + (size_t)grow * 256 + cg * 64 + (tt & 7) * 8) =
                *(const i32x4*)&cs[row][(tt & 7) * 8];
    }
}

// ---------------- layer-2 GEMM v2: t = A@W1 (bf16), u = A@W2 + bias (fp32) ----------------
__global__ __launch_bounds__(256) void gemm2_v2(const uint16_t* __restrict__ A,
                                                const uint16_t* __restrict__ W1sw,
                                                const uint16_t* __restrict__ W2sw,
                                                const uint16_t* __restrict__ bias,
                                                uint16_t* __restrict__ T,
                                                float* __restrict__ U) {
    __shared__ __align__(16) uint16_t ts[64][72];   // 9216 B
    __shared__ __align__(16) float us[64][68];      // 17408 B
    int wg = xcd_swz(blockIdx.x, 1564);
    int rg = wg >> 1, cg = wg & 1;
    int wave = threadIdx.x >> 6, lane = threadIdx.x & 63;
    int wr = wave >> 1, wc = wave & 1;
    int m = lane & 15, q = lane >> 4;
    int rowbase = rg * 64 + wr * 32;
    int gnt0 = cg * 4 + wc * 2;      // global 16-col frag base, NTF=8

    int ar[2];
#pragma unroll
    for (int rf = 0; rf < 2; rf++) {
        int r = rowbase + rf * 16 + m;
        ar[rf] = (r < NN) ? r : (NN - 1);
    }

    f32x4 acc1[2][2], acc2[2][2];
#pragma unroll
    for (int rf = 0; rf < 2; rf++)
#pragma unroll
        for (int nt = 0; nt < 2; nt++)
#pragma unroll
            for (int i = 0; i < 4; i++) { acc1[rf][nt][i] = 0.f; acc2[rf][nt][i] = 0.f; }

    // ---- pass 1: A @ W1 -> acc1 ----
    {
        bf16x8 B[8][2];
#pragma unroll
        for (int kt = 0; kt < 8; kt++)
#pragma unroll
            for (int nt = 0; nt < 2; nt++)
                B[kt][nt] = *(const bf16x8*)(W1sw + ((size_t)(kt * 8 + gnt0 + nt)) * 512 + lane * 8);
#pragma unroll
        for (int kt = 0; kt < 8; kt++) {
            bf16x8 a0 = *(const bf16x8*)(A + (size_t)ar[0] * 256 + kt * 32 + q * 8);
            bf16x8 a1 = *(const bf16x8*)(A + (size_t)ar[1] * 256 + kt * 32 + q * 8);
#pragma unroll
            for (int nt = 0; nt < 2; nt++) {
                acc1[0][nt] = __builtin_amdgcn_mfma_f32_16x16x32_bf16(a0, B[kt][nt], acc1[0][nt], 0, 0, 0);
                acc1[1][nt] = __builtin_amdgcn_mfma_f32_16x16x32_bf16(a1, B[kt][nt], acc1[1][nt], 0, 0, 0);
            }
        }
    }
    asm volatile("" ::: "memory");   // fence: cap live B regs at one pass's worth
    // ---- pass 2: A @ W2 -> acc2 ----
    {
        bf16x8 B[8][2];
#pragma unroll
        for (int kt = 0; kt < 8; kt++)
#pragma unroll
            for (int nt = 0; nt < 2; nt++)
                B[kt][nt] = *(const bf16x8*)(W2sw + ((size_t)(kt * 8 + gnt0 + nt)) * 512 + lane * 8);
#pragma unroll
        for (int kt = 0; kt < 8; kt++) {
            bf16x8 a0 = *(const bf16x8*)(A + (size_t)ar[0] * 256 + kt * 32 + q * 8);
            bf16x8 a1 = *(const bf16x8*)(A + (size_t)ar[1] * 256 + kt * 32 + q * 8);
#pragma unroll
            for (int nt = 0; nt < 2; nt++) {
                acc2[0][nt] = __builtin_amdgcn_mfma_f32_16x16x32_bf16(a0, B[kt][nt], acc2[0][nt], 0, 0, 0);
                acc2[1][nt] = __builtin_amdgcn_mfma_f32_16x16x32_bf16(a1, B[kt][nt], acc2[1][nt], 0, 0, 0);
            }
        }
    }

    // ---- epilogue: t (raw bf16) and u (bias-added fp32) via LDS, coalesced ----
#pragma unroll
    for (int rf = 0; rf < 2; rf++)
#pragma unroll
        for (int nt = 0; nt < 2; nt++) {
            int coll = wc * 32 + nt * 16 + m;
            float bv = bf2f(bias[cg * 64 + coll]);
#pragma unroll
            for (int i = 0; i < 4; i++) {
                int rl = wr * 32 + rf * 16 + q * 4 + i;
                ts[rl][coll] = f2bf(acc1[rf][nt][i]);
                us[rl][coll] = acc2[rf][nt][i] + bv;
            }
        }
    __syncthreads();
    int tt = threadIdx.x;
#pragma unroll
    for (int rr = 0; rr < 2; rr++) {
        int row = rr * 32 + (tt >> 3);
        int grow = rg * 64 + row;
        if (grow < NN)
            *(i32x4*)(T + (size_t)grow * 128 + cg * 64 + (tt & 7) * 8) =
                *(const i32x4*)&ts[row][(tt & 7) * 8];
    }
#pragma unroll
    for (int rr = 0; rr < 4; rr++) {
        int row = rr * 16 + (tt >> 4);
        int grow = rg * 64 + row;
        if (grow < NN)
            *(f32x4*)(U + (size_t)grow * 128 + cg * 64 + (tt & 15) * 4) =
                *(const f32x4*)&us[row][(tt & 15) * 4];
    }
}

extern "C" void kernel_launch(void* const* d_in, const int* in_sizes, int n_in,
                              void* d_out, int out_size, void* d_ws, size_t ws_size,
                              hipStream_t stream) {
    const void* x_raw  = d_in[0];
    const int*  ei     = (const int*)d_in[1];
    const void* W1l    = d_in[2];
    const void* b1     = d_in[3];
    const void* W1r    = d_in[4];
    const void* W2l    = d_in[5];
    const void* b2     = d_in[6];
    const void* W2r    = d_in[7];

    uint8_t* ws = (uint8_t*)d_ws;
    size_t off = 0;
    auto alloc = [&](size_t b) -> void* {
        void* p = ws + off;
        off += (b + 255) & ~(size_t)255;
        return p;
    };
    int*      flags       = (int*)alloc(256);
    int*      histM       = (int*)alloc((size_t)NB * NBLK * 4);
    int*      bucket_tot  = (int*)alloc((NB + 4) * 4);
    int*      bucket_base = (int*)alloc((NB + 4) * 4);
    int*      deg         = (int*)alloc((size_t)NN * 4);
    float*    inv_deg     = (float*)alloc((size_t)NN * 4);
    int*      row_start   = (int*)alloc((size_t)NN * 4);
    int*      csr         = (int*)alloc((size_t)NE * 4);
    uint32_t* xb          = (uint32_t*)alloc((size_t)NN * 64 * 4);
    uint16_t* bias_buf    = (uint16_t*)alloc(384 * 2);
    uint16_t* agg         = (uint16_t*)alloc((size_t)NN * 128 * 2);
    uint16_t* h           = (uint16_t*)alloc((size_t)NN * 256 * 2);
    uint16_t* t           = (uint16_t*)alloc((size_t)NN * 128 * 2);
    float*    u           = (float*)alloc((size_t)NN * 128 * 4);
    uint16_t* w1l_sw      = (uint16_t*)alloc(128 * 256 * 2);
    uint16_t* w1r_sw      = (uint16_t*)alloc(128 * 256 * 2);
    uint16_t* w2l_sw      = (uint16_t*)alloc(256 * 128 * 2);
    uint16_t* w2r_sw      = (uint16_t*)alloc(256 * 128 * 2);

    // staging aliases h (3.2 MB <= 25.6 MB; fully consumed by build_csr before h is written)
    uint32_t* staging = (uint32_t*)h;

    detect<<<1, 256, 0, stream>>>((const uint32_t*)x_raw, ei, flags);

    hist_pass<<<NBLK, 256, 0, stream>>>(ei, flags, histM);
    scan_rows<<<NB, 512, 0, stream>>>(histM, bucket_tot);
    scan_tot<<<1, 256, 0, stream>>>(bucket_tot, bucket_base);
    scatter_pass<<<NBLK, 256, 0, stream>>>(ei, flags, histM, bucket_base, staging);
    build_csr<<<NB, 256, 0, stream>>>(staging, bucket_base, row_start, deg, inv_deg, csr);

    norm_x<<<(NN * 32 + 255) / 256, 256, 0, stream>>>(x_raw, flags, xb);
    norm_weights_sw<<<66, 256, 0, stream>>>(W1l, b1, W1r, W2l, b2, W2r, flags,
                                            w1l_sw, w1r_sw, w2l_sw, w2r_sw, bias_buf);

    // layer 1: agg = A·x ; h = relu(agg@W1l + x@W1r + b1)
    agg_mean_v2<<<NN / 8, 256, 0, stream>>>(xb, row_start, deg, csr, inv_deg, (uint32_t*)agg);
    gemm1_v2<<<3128, 256, 0, stream>>>(agg, (const uint16_t*)xb, w1l_sw, w1r_sw, bias_buf, h);
    // layer 2: t = h@W2l, u = h@W2r + b2 ; out = A·t + u
    gemm2_v2<<<1564, 256, 0, stream>>>(h, w2l_sw, w2r_sw, bias_buf + 256, t, u);
    agg_final_v2<<<NN / 8, 256, 0, stream>>>((const uint32_t*)t, row_start, deg, csr, inv_deg,
                                             (const f32x4*)u, (f32x4*)d_out);
}